// Round 5
// baseline (546.519 us; speedup 1.0000x reference)
//
#include <hip/hip_runtime.h>
#include <hip/hip_bf16.h>
#include <math.h>
#include <stdint.h>

#define BT  4096
#define DIM 1024
#define HID 4096
#define NE  8
#define TMX2 40   // max active 256-row m-blocks (32 full + 8 partial)

typedef __attribute__((ext_vector_type(8))) short short8v;
typedef __attribute__((ext_vector_type(4))) float f32x4;
typedef unsigned short ushort_t;

typedef __attribute__((address_space(1))) const void gas_void;
typedef __attribute__((address_space(3))) void las_void;
#define GLOAD_LDS16(g, l) __builtin_amdgcn_global_load_lds((gas_void*)(g), (las_void*)(l), 16, 0, 0)

__device__ inline ushort_t f2bf(float f) {
  __hip_bfloat16 b = __float2bfloat16(f);
  union { __hip_bfloat16 h; ushort_t u; } cv;
  cv.h = b;
  return cv.u;
}

// -------- fused prep + router: one block per token --------
// 256 thr: each converts 4 floats of x -> bf16 AND accumulates 4x8 logits FMA.
__global__ __launch_bounds__(256) void k_prep_router(
    const float* __restrict__ x, const float* __restrict__ wg,
    ushort_t* __restrict__ xbf, float* __restrict__ logits_out,
    float* __restrict__ probs01, int* __restrict__ assign,
    int* __restrict__ cur) {
  int t = blockIdx.x;
  int tid = threadIdx.x;
  const float* xr = x + (size_t)t * DIM;
  float4 v = ((const float4*)xr)[tid];
  ushort4 o;
  o.x = f2bf(v.x); o.y = f2bf(v.y); o.z = f2bf(v.z); o.w = f2bf(v.w);
  ((ushort4*)(xbf + (size_t)t * DIM))[tid] = o;

  float vv[4] = {v.x, v.y, v.z, v.w};
  float part[NE];
#pragma unroll
  for (int e = 0; e < NE; e++) part[e] = 0.f;
#pragma unroll
  for (int i = 0; i < 4; i++) {
    const float4* wr = (const float4*)(wg + (size_t)(tid * 4 + i) * NE);
    float4 a = wr[0], b = wr[1];
    part[0] += vv[i] * a.x; part[1] += vv[i] * a.y;
    part[2] += vv[i] * a.z; part[3] += vv[i] * a.w;
    part[4] += vv[i] * b.x; part[5] += vv[i] * b.y;
    part[6] += vv[i] * b.z; part[7] += vv[i] * b.w;
  }
#pragma unroll
  for (int e = 0; e < NE; e++)
    for (int off = 32; off > 0; off >>= 1)
      part[e] += __shfl_xor(part[e], off);

  __shared__ float red[4][NE];
  int lane = tid & 63, wv = tid >> 6;
  if (lane == 0) {
#pragma unroll
    for (int e = 0; e < NE; e++) red[wv][e] = part[e];
  }
  __syncthreads();
  if (tid == 0) {
    float s8[NE];
#pragma unroll
    for (int e = 0; e < NE; e++)
      s8[e] = red[0][e] + red[1][e] + red[2][e] + red[3][e];
    float m = s8[0];
    for (int e = 1; e < NE; e++) m = fmaxf(m, s8[e]);
    float p[NE], s = 0.f;
    for (int e = 0; e < NE; e++) { p[e] = expf(s8[e] - m); s += p[e]; }
    float inv = 1.f / s;
    for (int e = 0; e < NE; e++) p[e] *= inv;
    for (int e = 0; e < NE; e++) logits_out[(size_t)t * NE + e] = s8[e];
    probs01[t * 2 + 0] = p[0];
    probs01[t * 2 + 1] = p[1];
    int b0 = 0;
    for (int e = 1; e < NE; e++) if (p[e] > p[b0]) b0 = e;
    int b1 = (b0 == 0) ? 1 : 0;
    for (int e = 0; e < NE; e++) if (e != b0 && p[e] > p[b1]) b1 = e;
    int pos0 = atomicAdd(&cur[b0], 1);
    assign[b0 * BT + pos0] = t * 2 + 0;
    int pos1 = atomicAdd(&cur[b1], 1);
    assign[b1 * BT + pos1] = t * 2 + 1;
  }
}

// -------- transpose+convert: src fp32 [E][R][C] -> dst bf16 [E][C][R] --------
// 16B (ushort8) stores; LDS read side is 2-way-aliased only (free).
__global__ __launch_bounds__(256) void k_transpose(const float* __restrict__ src,
                                                   ushort_t* __restrict__ dst,
                                                   int R, int C) {
  __shared__ float tile[64][65];
  int e = blockIdx.z;
  const float* s = src + (size_t)e * R * C;
  ushort_t* d = dst + (size_t)e * R * C;
  int c0 = blockIdx.x * 64, r0 = blockIdx.y * 64;
  int t = threadIdx.x;
  int lr = t >> 4;
  int lc4 = (t & 15) * 4;
#pragma unroll
  for (int i = 0; i < 4; i++) {
    int r = lr + 16 * i;
    float4 v = *(const float4*)&s[(size_t)(r0 + r) * C + c0 + lc4];
    tile[r][lc4 + 0] = v.x; tile[r][lc4 + 1] = v.y;
    tile[r][lc4 + 2] = v.z; tile[r][lc4 + 3] = v.w;
  }
  __syncthreads();
  int c = t >> 3, r8 = (t & 7) * 8;
#pragma unroll
  for (int p = 0; p < 2; p++) {
    int cc = c + 32 * p;
    short8v ov;
#pragma unroll
    for (int i = 0; i < 8; i++) ov[i] = (short)f2bf(tile[r8 + i][cc]);
    *(short8v*)&d[(size_t)(c0 + cc) * R + r0 + r8] = ov;
  }
}

// -------- plan: prefix offsets + flattened active 256-row block list --------
__global__ void k_plan(const int* __restrict__ cur, int* __restrict__ segoff,
                       int* __restrict__ blk2_e, int* __restrict__ blk2_m0) {
  __shared__ int sc[NE];
  int tid = threadIdx.x;
  if (tid < NE) sc[tid] = cur[tid];
  __syncthreads();
  if (tid == 0 && blockIdx.x == 0) {
    int s = 0;
    for (int e = 0; e < NE; e++) { segoff[e] = s; s += sc[e]; }
    int t = 0;
    for (int e = 0; e < NE; e++) {
      int mb = (sc[e] + 255) >> 8;
      for (int i = 0; i < mb; i++) { blk2_e[t] = e; blk2_m0[t] = i << 8; t++; }
    }
    for (; t < TMX2; t++) { blk2_e[t] = -1; blk2_m0[t] = 0; }
  }
}

// ============================================================================
// Shared K-tile body for both GEMMs (256x256 tile, BK=32, ring-4 LDS 128 KiB,
// 8 waves as 2M x 4N, wave tile 128x64, acc[8][4]).
// Per K-tile: TWO phases, each {ds_reads -> stage-unit -> [vmcnt] -> barrier
// -> setprio -> 16 MFMA}. Reads are issued BEFORE the barrier so the barrier
// wait absorbs ds_read latency. Staging staggered: F2S = B-calls of tile t+3
// issued in P1(t); L2S = A-calls of tile t+2 issued in P0(t).
// Boundary vmcnt(6) at end of P1(t) drains tile t+1's 4 loads. Tail: 6,4,0.
// ============================================================================
#define VM6 asm volatile("s_waitcnt vmcnt(6)" ::: "memory")
#define VM4 asm volatile("s_waitcnt vmcnt(4)" ::: "memory")
#define VM0 asm volatile("s_waitcnt vmcnt(0)" ::: "memory")
#define VMN do {} while (0)

#define TILEK(TB, T, VMX, DOL2, DOF2)                                           \
  { short8v bv[4], afl[4];                                                      \
    _Pragma("unroll")                                                           \
    for (int n = 0; n < 4; n++)                                                 \
      bv[n] = *(const short8v*)&Bv[TB][wn * 64 + n * 16 + lr][xsw];             \
    _Pragma("unroll")                                                           \
    for (int m = 0; m < 4; m++)                                                 \
      afl[m] = *(const short8v*)&A[TB][wm * 128 + m * 16 + lr][xsw];            \
    if (DOL2) { L2S((((TB) + 2) & 3), ((T) + 2) * 32); }                        \
    __builtin_amdgcn_s_barrier();                                               \
    __builtin_amdgcn_sched_barrier(0);                                          \
    __builtin_amdgcn_s_setprio(1);                                              \
    _Pragma("unroll")                                                           \
    for (int m = 0; m < 4; m++)                                                 \
      _Pragma("unroll")                                                         \
      for (int n = 0; n < 4; n++)                                               \
        acc[m][n] = __builtin_amdgcn_mfma_f32_16x16x32_bf16(afl[m], bv[n],      \
                                                            acc[m][n], 0, 0, 0);\
    __builtin_amdgcn_s_setprio(0);                                              \
    short8v afh[4];                                                             \
    _Pragma("unroll")                                                           \
    for (int m = 0; m < 4; m++)                                                 \
      afh[m] = *(const short8v*)&A[TB][wm * 128 + 64 + m * 16 + lr][xsw];       \
    if (DOF2) { F2S((((TB) + 3) & 3), ((T) + 3) * 32); }                        \
    VMX;                                                                        \
    __builtin_amdgcn_s_barrier();                                               \
    __builtin_amdgcn_sched_barrier(0);                                          \
    __builtin_amdgcn_s_setprio(1);                                              \
    _Pragma("unroll")                                                           \
    for (int m = 0; m < 4; m++)                                                 \
      _Pragma("unroll")                                                         \
      for (int n = 0; n < 4; n++)                                               \
        acc[4 + m][n] = __builtin_amdgcn_mfma_f32_16x16x32_bf16(afh[m], bv[n],  \
                                                        acc[4 + m][n], 0, 0, 0);\
    __builtin_amdgcn_s_setprio(0); }

// ============================================================================
// GEMM1: h = gelu(x_gathered @ w1^T + b1).  Grid 16*TMX2 = 640.
// ============================================================================
__global__ __launch_bounds__(512, 2) void k_gemm1(
    const ushort_t* __restrict__ xbf, const ushort_t* __restrict__ wt1,
    const float* __restrict__ b1,
    const int* __restrict__ assign, const int* __restrict__ cur,
    const int* __restrict__ segoff, const int* __restrict__ blk2_e,
    const int* __restrict__ blk2_m0, ushort_t* __restrict__ hbuf) {
  const int nwg = 16 * TMX2;                   // 640, divisible by 8
  int f = blockIdx.x;
  int lg = (f & 7) * (nwg >> 3) + (f >> 3);    // XCD chunk swizzle (bijective)
  int m_idx = lg % TMX2;                       // m-inner: chunk reuses B-panels
  int n_idx = lg / TMX2;
  int e = blk2_e[m_idx];
  if (e < 0) return;
  int m0 = blk2_m0[m_idx];
  int count = cur[e];
  int n0 = n_idx << 8;

  __shared__ __attribute__((aligned(16))) ushort_t A[4][256][32];
  __shared__ __attribute__((aligned(16))) ushort_t Bv[4][256][32];
  int tid = threadIdx.x;
  int lane = tid & 63, wid = tid >> 6;

  int srow = lane >> 2;
  int sunit = ((lane & 3) ^ ((lane >> 3) & 3)) << 3;
  int pA0 = m0 + wid * 16 + srow;
  int pA1 = pA0 + 128;
  int tok0 = (pA0 < count) ? (assign[e * BT + pA0] >> 1) : 0;
  int tok1 = (pA1 < count) ? (assign[e * BT + pA1] >> 1) : 0;
  const ushort_t* gA0 = xbf + (size_t)tok0 * DIM + sunit;
  const ushort_t* gA1 = xbf + (size_t)tok1 * DIM + sunit;
  const ushort_t* gB0 = wt1 + ((size_t)e * HID + n0 + wid * 16 + srow) * DIM + sunit;
  const ushort_t* gB1 = gB0 + (size_t)128 * DIM;

  int wm = wid >> 2, wn = wid & 3;             // wave tile: 128(m) x 64(n)
  int lr = lane & 15, g = lane >> 4;
  int xsw = ((g ^ ((lr >> 1) & 3)) << 3);
  f32x4 acc[8][4];
  f32x4 zero = {0.f, 0.f, 0.f, 0.f};
#pragma unroll
  for (int m = 0; m < 8; m++)
#pragma unroll
    for (int n = 0; n < 4; n++) acc[m][n] = zero;

#define F2S(SL, K0)                                            \
  { GLOAD_LDS16(gB0 + (K0), &Bv[SL][wid * 16][0]);             \
    GLOAD_LDS16(gB1 + (K0), &Bv[SL][128 + wid * 16][0]); }
#define L2S(SL, K0)                                            \
  { GLOAD_LDS16(gA0 + (K0), &A[SL][wid * 16][0]);              \
    GLOAD_LDS16(gA1 + (K0), &A[SL][128 + wid * 16][0]); }

  F2S(0, 0);  L2S(0, 0);
  F2S(1, 32); L2S(1, 32);
  F2S(2, 64);
  VM6;
  __builtin_amdgcn_s_barrier();
  __builtin_amdgcn_sched_barrier(0);

  const int NT = DIM / 32;                     // 32
  for (int t = 0; t < NT - 4; t += 4) {
    TILEK(0, t + 0, VM6, 1, 1);
    TILEK(1, t + 1, VM6, 1, 1);
    TILEK(2, t + 2, VM6, 1, 1);
    TILEK(3, t + 3, VM6, 1, 1);
  }
  TILEK(0, NT - 4, VM6, 1, 1);
  TILEK(1, NT - 3, VM4, 1, 0);
  TILEK(2, NT - 2, VM0, 0, 0);
  TILEK(3, NT - 1, VMN, 0, 0);
#undef F2S
#undef L2S

  int so = segoff[e];
#pragma unroll
  for (int m = 0; m < 8; m++) {
#pragma unroll
    for (int j = 0; j < 4; j++) {
      int p = m0 + wm * 128 + m * 16 + g * 4 + j;
      if (p >= count) continue;
      ushort_t* hr = hbuf + (size_t)(so + p) * HID;
#pragma unroll
      for (int n = 0; n < 4; n++) {
        int col = n0 + wn * 64 + n * 16 + lr;
        float v = acc[m][n][j] + b1[e * HID + col];
        float gl = 0.5f * v * (1.0f + erff(v * 0.70710678118654752f));
        hr[col] = f2bf(gl);
      }
    }
  }
}

// ============================================================================
// GEMM2: out[t] += (h @ w2^T + b2) * probs01[t][slot]   (atomicAdd epilogue)
// 256x256 tile, grid 4*TMX2 = 160.  Exactly 2 contention-free contributors
// per out element; fp add is commutative -> deterministic.
// ============================================================================
__global__ __launch_bounds__(512, 2) void k_gemm2(
    const ushort_t* __restrict__ hbuf, const ushort_t* __restrict__ wt2,
    const float* __restrict__ b2,
    const int* __restrict__ assign, const int* __restrict__ cur,
    const int* __restrict__ segoff, const int* __restrict__ blk2_e,
    const int* __restrict__ blk2_m0, const float* __restrict__ probs01,
    float* __restrict__ out) {
  const int nwg = 4 * TMX2;                    // 160, divisible by 8
  int f = blockIdx.x;
  int lg = (f & 7) * (nwg >> 3) + (f >> 3);
  int m_idx = lg % TMX2;
  int n_idx = lg / TMX2;
  int e = blk2_e[m_idx];
  if (e < 0) return;
  int m0 = blk2_m0[m_idx];
  int count = cur[e];
  int n0 = n_idx << 8;
  int so = segoff[e];

  __shared__ __attribute__((aligned(16))) ushort_t A[4][256][32];
  __shared__ __attribute__((aligned(16))) ushort_t Bv[4][256][32];
  int tid = threadIdx.x;
  int lane = tid & 63, wid = tid >> 6;

  int srow = lane >> 2;
  int sunit = ((lane & 3) ^ ((lane >> 3) & 3)) << 3;
  int pA0 = m0 + wid * 16 + srow;
  int pA1 = pA0 + 128;
  int pa0 = (pA0 < count) ? pA0 : (count - 1);
  int pa1 = (pA1 < count) ? pA1 : (count - 1);
  const ushort_t* gA0 = hbuf + (size_t)(so + pa0) * HID + sunit;
  const ushort_t* gA1 = hbuf + (size_t)(so + pa1) * HID + sunit;
  const ushort_t* gB0 = wt2 + ((size_t)e * DIM + n0 + wid * 16 + srow) * HID + sunit;
  const ushort_t* gB1 = gB0 + (size_t)128 * HID;

  int wm = wid >> 2, wn = wid & 3;             // wave tile: 128(m) x 64(n)
  int lr = lane & 15, g = lane >> 4;
  int xsw = ((g ^ ((lr >> 1) & 3)) << 3);
  f32x4 acc[8][4];
  f32x4 zero = {0.f, 0.f, 0.f, 0.f};
#pragma unroll
  for (int m = 0; m < 8; m++)
#pragma unroll
    for (int n = 0; n < 4; n++) acc[m][n] = zero;

#define F2S(SL, K0)                                            \
  { GLOAD_LDS16(gB0 + (K0), &Bv[SL][wid * 16][0]);             \
    GLOAD_LDS16(gB1 + (K0), &Bv[SL][128 + wid * 16][0]); }
#define L2S(SL, K0)                                            \
  { GLOAD_LDS16(gA0 + (K0), &A[SL][wid * 16][0]);              \
    GLOAD_LDS16(gA1 + (K0), &A[SL][128 + wid * 16][0]); }

  F2S(0, 0);  L2S(0, 0);
  F2S(1, 32); L2S(1, 32);
  F2S(2, 64);
  VM6;
  __builtin_amdgcn_s_barrier();
  __builtin_amdgcn_sched_barrier(0);

  const int NT = HID / 32;                     // 128
  for (int t = 0; t < NT - 4; t += 4) {
    TILEK(0, t + 0, VM6, 1, 1);
    TILEK(1, t + 1, VM6, 1, 1);
    TILEK(2, t + 2, VM6, 1, 1);
    TILEK(3, t + 3, VM6, 1, 1);
  }
  TILEK(0, NT - 4, VM6, 1, 1);
  TILEK(1, NT - 3, VM4, 1, 0);
  TILEK(2, NT - 2, VM0, 0, 0);
  TILEK(3, NT - 1, VMN, 0, 0);
#undef F2S
#undef L2S

#pragma unroll
  for (int m = 0; m < 8; m++) {
#pragma unroll
    for (int j = 0; j < 4; j++) {
      int p = m0 + wm * 128 + m * 16 + g * 4 + j;
      if (p >= count) continue;
      int a = assign[e * BT + p];
      int t = a >> 1, slot = a & 1;
      float w = probs01[t * 2 + slot];
      float* orow = out + (size_t)t * DIM;
#pragma unroll
      for (int n = 0; n < 4; n++) {
        int col = n0 + wn * 64 + n * 16 + lr;
        atomicAdd(&orow[col], (acc[m][n][j] + b2[e * DIM + col]) * w);
      }
    }
  }
}

extern "C" void kernel_launch(void* const* d_in, const int* in_sizes, int n_in,
                              void* d_out, int out_size, void* d_ws, size_t ws_size,
                              hipStream_t stream) {
  const float* x  = (const float*)d_in[0];
  const float* wg = (const float*)d_in[1];
  const float* w1 = (const float*)d_in[2];
  const float* b1 = (const float*)d_in[3];
  const float* w2 = (const float*)d_in[4];
  const float* b2 = (const float*)d_in[5];
  float* out = (float*)d_out;
  float* logits_out = out + (size_t)BT * DIM;

  char* ws = (char*)d_ws;
  size_t off = 0;
  auto alloc = [&](size_t bytes) -> void* {
    void* p = ws + off;
    off = (off + bytes + 255) & ~(size_t)255;
    return p;
  };
  ushort_t* xbf    = (ushort_t*)alloc((size_t)BT * DIM * 2);
  ushort_t* wt1    = (ushort_t*)alloc((size_t)NE * HID * DIM * 2);
  ushort_t* wt2    = (ushort_t*)alloc((size_t)NE * DIM * HID * 2);
  ushort_t* hbuf   = (ushort_t*)alloc((size_t)2 * BT * HID * 2);
  float*    probs01= (float*)alloc((size_t)BT * 2 * 4);
  int*      assign = (int*)alloc((size_t)NE * BT * 4);
  int*      cur    = (int*)alloc(64);
  int*      segoff = (int*)alloc(64);
  int*      blk2_e = (int*)alloc(TMX2 * 4);
  int*      blk2_m0= (int*)alloc(TMX2 * 4);
  if (off > ws_size) return;

  hipMemsetAsync(cur, 0, NE * sizeof(int), stream);
  hipMemsetAsync(out, 0, (size_t)BT * DIM * sizeof(float), stream);
  hipLaunchKernelGGL(k_prep_router, dim3(BT), dim3(256), 0, stream,
                     x, wg, xbf, logits_out, probs01, assign, cur);
  hipLaunchKernelGGL(k_transpose, dim3(HID / 64, DIM / 64, NE), dim3(256), 0, stream,
                     w1, wt1, DIM, HID);
  hipLaunchKernelGGL(k_transpose, dim3(DIM / 64, HID / 64, NE), dim3(256), 0, stream,
                     w2, wt2, HID, DIM);
  hipLaunchKernelGGL(k_plan, dim3(1), dim3(64), 0, stream, cur, segoff,
                     blk2_e, blk2_m0);
  hipLaunchKernelGGL(k_gemm1, dim3(16 * TMX2), dim3(512), 0, stream,
                     xbf, wt1, b1, assign, cur, segoff, blk2_e, blk2_m0, hbuf);
  hipLaunchKernelGGL(k_gemm2, dim3(4 * TMX2), dim3(512), 0, stream,
                     hbuf, wt2, b2, assign, cur, segoff, blk2_e, blk2_m0,
                     probs01, out);
}

// Round 6
// 501.542 us; speedup vs baseline: 1.0897x; 1.0897x over previous
//
#include <hip/hip_runtime.h>
#include <hip/hip_bf16.h>
#include <math.h>
#include <stdint.h>

#define BT  4096
#define DIM 1024
#define HID 4096
#define NE  8
#define TMX2 40   // max active 256-row m-blocks (32 full + 8 partial)

typedef __attribute__((ext_vector_type(8))) short short8v;
typedef __attribute__((ext_vector_type(4))) float f32x4;
typedef unsigned short ushort_t;

typedef __attribute__((address_space(1))) const void gas_void;
typedef __attribute__((address_space(3))) void las_void;
#define GLOAD_LDS16(g, l) __builtin_amdgcn_global_load_lds((gas_void*)(g), (las_void*)(l), 16, 0, 0)

__device__ inline ushort_t f2bf(float f) {
  __hip_bfloat16 b = __float2bfloat16(f);
  union { __hip_bfloat16 h; ushort_t u; } cv;
  cv.h = b;
  return cv.u;
}

// -------- fused prep + router: one block per token --------
__global__ __launch_bounds__(256) void k_prep_router(
    const float* __restrict__ x, const float* __restrict__ wg,
    ushort_t* __restrict__ xbf, float* __restrict__ logits_out,
    float* __restrict__ probs01, int* __restrict__ assign,
    int* __restrict__ cur) {
  int t = blockIdx.x;
  int tid = threadIdx.x;
  const float* xr = x + (size_t)t * DIM;
  float4 v = ((const float4*)xr)[tid];
  ushort4 o;
  o.x = f2bf(v.x); o.y = f2bf(v.y); o.z = f2bf(v.z); o.w = f2bf(v.w);
  ((ushort4*)(xbf + (size_t)t * DIM))[tid] = o;

  float vv[4] = {v.x, v.y, v.z, v.w};
  float part[NE];
#pragma unroll
  for (int e = 0; e < NE; e++) part[e] = 0.f;
#pragma unroll
  for (int i = 0; i < 4; i++) {
    const float4* wr = (const float4*)(wg + (size_t)(tid * 4 + i) * NE);
    float4 a = wr[0], b = wr[1];
    part[0] += vv[i] * a.x; part[1] += vv[i] * a.y;
    part[2] += vv[i] * a.z; part[3] += vv[i] * a.w;
    part[4] += vv[i] * b.x; part[5] += vv[i] * b.y;
    part[6] += vv[i] * b.z; part[7] += vv[i] * b.w;
  }
#pragma unroll
  for (int e = 0; e < NE; e++)
    for (int off = 32; off > 0; off >>= 1)
      part[e] += __shfl_xor(part[e], off);

  __shared__ float red[4][NE];
  int lane = tid & 63, wv = tid >> 6;
  if (lane == 0) {
#pragma unroll
    for (int e = 0; e < NE; e++) red[wv][e] = part[e];
  }
  __syncthreads();
  if (tid == 0) {
    float s8[NE];
#pragma unroll
    for (int e = 0; e < NE; e++)
      s8[e] = red[0][e] + red[1][e] + red[2][e] + red[3][e];
    float m = s8[0];
    for (int e = 1; e < NE; e++) m = fmaxf(m, s8[e]);
    float p[NE], s = 0.f;
    for (int e = 0; e < NE; e++) { p[e] = expf(s8[e] - m); s += p[e]; }
    float inv = 1.f / s;
    for (int e = 0; e < NE; e++) p[e] *= inv;
    for (int e = 0; e < NE; e++) logits_out[(size_t)t * NE + e] = s8[e];
    probs01[t * 2 + 0] = p[0];
    probs01[t * 2 + 1] = p[1];
    int b0 = 0;
    for (int e = 1; e < NE; e++) if (p[e] > p[b0]) b0 = e;
    int b1 = (b0 == 0) ? 1 : 0;
    for (int e = 0; e < NE; e++) if (e != b0 && p[e] > p[b1]) b1 = e;
    int pos0 = atomicAdd(&cur[b0], 1);
    assign[b0 * BT + pos0] = t * 2 + 0;
    int pos1 = atomicAdd(&cur[b1], 1);
    assign[b1 * BT + pos1] = t * 2 + 1;
  }
}

// -------- transpose+convert: src fp32 [E][R][C] -> dst bf16 [E][C][R] --------
// Also zeros cur[] (runs before k_prep_router in stream order).
__global__ __launch_bounds__(256) void k_transpose(const float* __restrict__ src,
                                                   ushort_t* __restrict__ dst,
                                                   int R, int C,
                                                   int* __restrict__ cur) {
  if (cur && blockIdx.x == 0 && blockIdx.y == 0 && blockIdx.z == 0 &&
      threadIdx.x < NE)
    cur[threadIdx.x] = 0;
  __shared__ float tile[64][65];
  int e = blockIdx.z;
  const float* s = src + (size_t)e * R * C;
  ushort_t* d = dst + (size_t)e * R * C;
  int c0 = blockIdx.x * 64, r0 = blockIdx.y * 64;
  int t = threadIdx.x;
  int lr = t >> 4;
  int lc4 = (t & 15) * 4;
#pragma unroll
  for (int i = 0; i < 4; i++) {
    int r = lr + 16 * i;
    float4 v = *(const float4*)&s[(size_t)(r0 + r) * C + c0 + lc4];
    tile[r][lc4 + 0] = v.x; tile[r][lc4 + 1] = v.y;
    tile[r][lc4 + 2] = v.z; tile[r][lc4 + 3] = v.w;
  }
  __syncthreads();
  int c = t >> 3, r8 = (t & 7) * 8;
#pragma unroll
  for (int p = 0; p < 2; p++) {
    int cc = c + 32 * p;
    short8v ov;
#pragma unroll
    for (int i = 0; i < 8; i++) ov[i] = (short)f2bf(tile[r8 + i][cc]);
    *(short8v*)&d[(size_t)(c0 + cc) * R + r0 + r8] = ov;
  }
}

// -------- plan: prefix offsets + flattened active 256-row block list --------
__global__ void k_plan(const int* __restrict__ cur, int* __restrict__ segoff,
                       int* __restrict__ blk2_e, int* __restrict__ blk2_m0) {
  int tid = threadIdx.x;
  if (tid == 0 && blockIdx.x == 0) {
    int s = 0;
    for (int e = 0; e < NE; e++) { segoff[e] = s; s += cur[e]; }
    int t = 0;
    for (int e = 0; e < NE; e++) {
      int mb = (cur[e] + 255) >> 8;
      for (int i = 0; i < mb; i++) { blk2_e[t] = e; blk2_m0[t] = i << 8; t++; }
    }
    for (; t < TMX2; t++) { blk2_e[t] = -1; blk2_m0[t] = 0; }
  }
}

// ============================================================================
// K-tile body (256x256 tile, BK=32, ring-4 LDS 128 KiB, 8 waves 2Mx4N,
// wave tile 128x64, acc[8][4]).  SINGLE barrier per K-tile:
//   { 12 ds_reads(tile TB) -> stage L2S(t+2), F2S(t+3) -> vmcnt(6) ->
//     barrier (publishes tile t+1) -> sched_barrier -> setprio -> 32 MFMA }
// The barrier-wait absorbs ds_read latency; MFMA cluster = 32 per barrier.
// Slot safety: L2S(t+2) -> slot holding tile t-2 (dead >= 2 barriers);
// F2S(t+3) -> slot holding tile t-1, whose ds_reads were issued before
// barrier#(t-1) and return ~150cyc, while this gload (issued after that
// barrier) lands >= ~200cyc later -- same discipline as m201's stage_rc.
// vmcnt ledger per wave (4 loads/tile): steady vmcnt(6); tail 6,4,0.
// ============================================================================
#define VM6 asm volatile("s_waitcnt vmcnt(6)" ::: "memory")
#define VM4 asm volatile("s_waitcnt vmcnt(4)" ::: "memory")
#define VM0 asm volatile("s_waitcnt vmcnt(0)" ::: "memory")
#define VMN do {} while (0)

#define TILEK(TB, T, VMX, DOL2, DOF2)                                           \
  { short8v bv[4], afl[4], afh[4];                                              \
    _Pragma("unroll")                                                           \
    for (int n = 0; n < 4; n++)                                                 \
      bv[n] = *(const short8v*)&Bv[TB][wn * 64 + n * 16 + lr][xsw];             \
    _Pragma("unroll")                                                           \
    for (int m = 0; m < 4; m++) {                                               \
      afl[m] = *(const short8v*)&A[TB][wm * 128 + m * 16 + lr][xsw];            \
      afh[m] = *(const short8v*)&A[TB][wm * 128 + 64 + m * 16 + lr][xsw];       \
    }                                                                           \
    if (DOL2) { L2S((((TB) + 2) & 3), ((T) + 2) * 32); }                        \
    if (DOF2) { F2S((((TB) + 3) & 3), ((T) + 3) * 32); }                        \
    VMX;                                                                        \
    __builtin_amdgcn_s_barrier();                                               \
    __builtin_amdgcn_sched_barrier(0);                                          \
    __builtin_amdgcn_s_setprio(1);                                              \
    _Pragma("unroll")                                                           \
    for (int m = 0; m < 4; m++)                                                 \
      _Pragma("unroll")                                                         \
      for (int n = 0; n < 4; n++) {                                             \
        acc[m][n] = __builtin_amdgcn_mfma_f32_16x16x32_bf16(afl[m], bv[n],      \
                                                            acc[m][n], 0, 0, 0);\
        acc[4 + m][n] = __builtin_amdgcn_mfma_f32_16x16x32_bf16(afh[m], bv[n],  \
                                                        acc[4 + m][n], 0, 0, 0);\
      }                                                                         \
    __builtin_amdgcn_s_setprio(0); }

// ============================================================================
// GEMM1: h = gelu(x_gathered @ w1^T + b1).  Grid 16*TMX2 = 640.
// ============================================================================
__global__ __launch_bounds__(512, 2) void k_gemm1(
    const ushort_t* __restrict__ xbf, const ushort_t* __restrict__ wt1,
    const float* __restrict__ b1,
    const int* __restrict__ assign, const int* __restrict__ cur,
    const int* __restrict__ segoff, const int* __restrict__ blk2_e,
    const int* __restrict__ blk2_m0, ushort_t* __restrict__ hbuf) {
  const int nwg = 16 * TMX2;                   // 640, divisible by 8
  int f = blockIdx.x;
  int lg = (f & 7) * (nwg >> 3) + (f >> 3);    // XCD chunk swizzle (bijective)
  int m_idx = lg % TMX2;                       // m-inner: chunk reuses B-panels
  int n_idx = lg / TMX2;
  int e = blk2_e[m_idx];
  if (e < 0) return;
  int m0 = blk2_m0[m_idx];
  int count = cur[e];
  int n0 = n_idx << 8;

  __shared__ __attribute__((aligned(16))) ushort_t A[4][256][32];
  __shared__ __attribute__((aligned(16))) ushort_t Bv[4][256][32];
  int tid = threadIdx.x;
  int lane = tid & 63, wid = tid >> 6;

  int srow = lane >> 2;
  int sunit = ((lane & 3) ^ ((lane >> 3) & 3)) << 3;
  int pA0 = m0 + wid * 16 + srow;
  int pA1 = pA0 + 128;
  int tok0 = (pA0 < count) ? (assign[e * BT + pA0] >> 1) : 0;
  int tok1 = (pA1 < count) ? (assign[e * BT + pA1] >> 1) : 0;
  const ushort_t* gA0 = xbf + (size_t)tok0 * DIM + sunit;
  const ushort_t* gA1 = xbf + (size_t)tok1 * DIM + sunit;
  const ushort_t* gB0 = wt1 + ((size_t)e * HID + n0 + wid * 16 + srow) * DIM + sunit;
  const ushort_t* gB1 = gB0 + (size_t)128 * DIM;

  int wm = wid >> 2, wn = wid & 3;             // wave tile: 128(m) x 64(n)
  int lr = lane & 15, g = lane >> 4;
  int xsw = ((g ^ ((lr >> 1) & 3)) << 3);
  f32x4 acc[8][4];
  f32x4 zero = {0.f, 0.f, 0.f, 0.f};
#pragma unroll
  for (int m = 0; m < 8; m++)
#pragma unroll
    for (int n = 0; n < 4; n++) acc[m][n] = zero;

#define F2S(SL, K0)                                            \
  { GLOAD_LDS16(gB0 + (K0), &Bv[SL][wid * 16][0]);             \
    GLOAD_LDS16(gB1 + (K0), &Bv[SL][128 + wid * 16][0]); }
#define L2S(SL, K0)                                            \
  { GLOAD_LDS16(gA0 + (K0), &A[SL][wid * 16][0]);              \
    GLOAD_LDS16(gA1 + (K0), &A[SL][128 + wid * 16][0]); }

  F2S(0, 0);  L2S(0, 0);
  F2S(1, 32); L2S(1, 32);
  F2S(2, 64);
  VM6;
  __builtin_amdgcn_s_barrier();
  __builtin_amdgcn_sched_barrier(0);

  const int NT = DIM / 32;                     // 32
  for (int t = 0; t < NT - 4; t += 4) {
    TILEK(0, t + 0, VM6, 1, 1);
    TILEK(1, t + 1, VM6, 1, 1);
    TILEK(2, t + 2, VM6, 1, 1);
    TILEK(3, t + 3, VM6, 1, 1);
  }
  TILEK(0, NT - 4, VM6, 1, 1);
  TILEK(1, NT - 3, VM4, 1, 0);
  TILEK(2, NT - 2, VM0, 0, 0);
  TILEK(3, NT - 1, VMN, 0, 0);
#undef F2S
#undef L2S

  int so = segoff[e];
#pragma unroll
  for (int m = 0; m < 8; m++) {
#pragma unroll
    for (int j = 0; j < 4; j++) {
      int p = m0 + wm * 128 + m * 16 + g * 4 + j;
      if (p >= count) continue;
      ushort_t* hr = hbuf + (size_t)(so + p) * HID;
#pragma unroll
      for (int n = 0; n < 4; n++) {
        int col = n0 + wn * 64 + n * 16 + lr;
        float v = acc[m][n][j] + b1[e * HID + col];
        float gl = 0.5f * v * (1.0f + erff(v * 0.70710678118654752f));
        hr[col] = f2bf(gl);
      }
    }
  }
}

// ============================================================================
// GEMM2: contrib[slot][t] = h @ w2^T + b2.  256x256 tile, grid 4*TMX2 = 160.
// ============================================================================
__global__ __launch_bounds__(512, 2) void k_gemm2(
    const ushort_t* __restrict__ hbuf, const ushort_t* __restrict__ wt2,
    const float* __restrict__ b2,
    const int* __restrict__ assign, const int* __restrict__ cur,
    const int* __restrict__ segoff, const int* __restrict__ blk2_e,
    const int* __restrict__ blk2_m0, float* __restrict__ contrib) {
  const int nwg = 4 * TMX2;                    // 160, divisible by 8
  int f = blockIdx.x;
  int lg = (f & 7) * (nwg >> 3) + (f >> 3);
  int m_idx = lg % TMX2;
  int n_idx = lg / TMX2;
  int e = blk2_e[m_idx];
  if (e < 0) return;
  int m0 = blk2_m0[m_idx];
  int count = cur[e];
  int n0 = n_idx << 8;
  int so = segoff[e];

  __shared__ __attribute__((aligned(16))) ushort_t A[4][256][32];
  __shared__ __attribute__((aligned(16))) ushort_t Bv[4][256][32];
  int tid = threadIdx.x;
  int lane = tid & 63, wid = tid >> 6;

  int srow = lane >> 2;
  int sunit = ((lane & 3) ^ ((lane >> 3) & 3)) << 3;
  int pA0 = m0 + wid * 16 + srow;
  int pA1 = pA0 + 128;
  int pa0 = (pA0 < count) ? pA0 : (count - 1);
  int pa1 = (pA1 < count) ? pA1 : (count - 1);
  const ushort_t* gA0 = hbuf + (size_t)(so + pa0) * HID + sunit;
  const ushort_t* gA1 = hbuf + (size_t)(so + pa1) * HID + sunit;
  const ushort_t* gB0 = wt2 + ((size_t)e * DIM + n0 + wid * 16 + srow) * HID + sunit;
  const ushort_t* gB1 = gB0 + (size_t)128 * HID;

  int wm = wid >> 2, wn = wid & 3;             // wave tile: 128(m) x 64(n)
  int lr = lane & 15, g = lane >> 4;
  int xsw = ((g ^ ((lr >> 1) & 3)) << 3);
  f32x4 acc[8][4];
  f32x4 zero = {0.f, 0.f, 0.f, 0.f};
#pragma unroll
  for (int m = 0; m < 8; m++)
#pragma unroll
    for (int n = 0; n < 4; n++) acc[m][n] = zero;

#define F2S(SL, K0)                                            \
  { GLOAD_LDS16(gB0 + (K0), &Bv[SL][wid * 16][0]);             \
    GLOAD_LDS16(gB1 + (K0), &Bv[SL][128 + wid * 16][0]); }
#define L2S(SL, K0)                                            \
  { GLOAD_LDS16(gA0 + (K0), &A[SL][wid * 16][0]);              \
    GLOAD_LDS16(gA1 + (K0), &A[SL][128 + wid * 16][0]); }

  F2S(0, 0);  L2S(0, 0);
  F2S(1, 32); L2S(1, 32);
  F2S(2, 64);
  VM6;
  __builtin_amdgcn_s_barrier();
  __builtin_amdgcn_sched_barrier(0);

  const int NT = HID / 32;                     // 128
  for (int t = 0; t < NT - 4; t += 4) {
    TILEK(0, t + 0, VM6, 1, 1);
    TILEK(1, t + 1, VM6, 1, 1);
    TILEK(2, t + 2, VM6, 1, 1);
    TILEK(3, t + 3, VM6, 1, 1);
  }
  TILEK(0, NT - 4, VM6, 1, 1);
  TILEK(1, NT - 3, VM4, 1, 0);
  TILEK(2, NT - 2, VM0, 0, 0);
  TILEK(3, NT - 1, VMN, 0, 0);
#undef F2S
#undef L2S

#pragma unroll
  for (int m = 0; m < 8; m++) {
#pragma unroll
    for (int j = 0; j < 4; j++) {
      int p = m0 + wm * 128 + m * 16 + g * 4 + j;
      if (p >= count) continue;
      int a = assign[e * BT + p];
      int t = a >> 1, slot = a & 1;
      float* cr = contrib + ((size_t)slot * BT + t) * DIM;
#pragma unroll
      for (int n = 0; n < 4; n++) {
        int col = n0 + wn * 64 + n * 16 + lr;
        cr[col] = acc[m][n][j] + b2[e * DIM + col];
      }
    }
  }
}

// -------- combine: final = c0*probs[:,0] + c1*probs[:,1] --------
__global__ void k_combine(const float* __restrict__ contrib,
                          const float* __restrict__ probs01,
                          float* __restrict__ out) {
  int idx = blockIdx.x * blockDim.x + threadIdx.x;
  const int n4 = BT * DIM / 4;
  if (idx >= n4) return;
  int t = idx >> 8;
  float wA = probs01[t * 2 + 0], wB = probs01[t * 2 + 1];
  float4 c0 = ((const float4*)contrib)[idx];
  float4 c1 = ((const float4*)(contrib + (size_t)BT * DIM))[idx];
  float4 o;
  o.x = c0.x * wA + c1.x * wB;
  o.y = c0.y * wA + c1.y * wB;
  o.z = c0.z * wA + c1.z * wB;
  o.w = c0.w * wA + c1.w * wB;
  ((float4*)out)[idx] = o;
}

extern "C" void kernel_launch(void* const* d_in, const int* in_sizes, int n_in,
                              void* d_out, int out_size, void* d_ws, size_t ws_size,
                              hipStream_t stream) {
  const float* x  = (const float*)d_in[0];
  const float* wg = (const float*)d_in[1];
  const float* w1 = (const float*)d_in[2];
  const float* b1 = (const float*)d_in[3];
  const float* w2 = (const float*)d_in[4];
  const float* b2 = (const float*)d_in[5];
  float* out = (float*)d_out;
  float* logits_out = out + (size_t)BT * DIM;

  char* ws = (char*)d_ws;
  size_t off = 0;
  auto alloc = [&](size_t bytes) -> void* {
    void* p = ws + off;
    off = (off + bytes + 255) & ~(size_t)255;
    return p;
  };
  ushort_t* xbf    = (ushort_t*)alloc((size_t)BT * DIM * 2);
  ushort_t* wt1    = (ushort_t*)alloc((size_t)NE * HID * DIM * 2);
  ushort_t* wt2    = (ushort_t*)alloc((size_t)NE * DIM * HID * 2);
  ushort_t* hbuf   = (ushort_t*)alloc((size_t)2 * BT * HID * 2);
  float*    contrib= (float*)alloc((size_t)2 * BT * DIM * 4);
  float*    probs01= (float*)alloc((size_t)BT * 2 * 4);
  int*      assign = (int*)alloc((size_t)NE * BT * 4);
  int*      cur    = (int*)alloc(64);
  int*      segoff = (int*)alloc(64);
  int*      blk2_e = (int*)alloc(TMX2 * 4);
  int*      blk2_m0= (int*)alloc(TMX2 * 4);
  if (off > ws_size) return;

  // transpose(w1) also zeros cur; stream order puts it before k_prep_router.
  hipLaunchKernelGGL(k_transpose, dim3(HID / 64, DIM / 64, NE), dim3(256), 0, stream,
                     w1, wt1, DIM, HID, cur);
  hipLaunchKernelGGL(k_transpose, dim3(DIM / 64, HID / 64, NE), dim3(256), 0, stream,
                     w2, wt2, HID, DIM, (int*)nullptr);
  hipLaunchKernelGGL(k_prep_router, dim3(BT), dim3(256), 0, stream,
                     x, wg, xbf, logits_out, probs01, assign, cur);
  hipLaunchKernelGGL(k_plan, dim3(1), dim3(64), 0, stream, cur, segoff,
                     blk2_e, blk2_m0);
  hipLaunchKernelGGL(k_gemm1, dim3(16 * TMX2), dim3(512), 0, stream,
                     xbf, wt1, b1, assign, cur, segoff, blk2_e, blk2_m0, hbuf);
  hipLaunchKernelGGL(k_gemm2, dim3(4 * TMX2), dim3(512), 0, stream,
                     hbuf, wt2, b2, assign, cur, segoff, blk2_e, blk2_m0, contrib);
  hipLaunchKernelGGL(k_combine, dim3((BT * DIM / 4 + 255) / 256), dim3(256), 0, stream,
                     contrib, probs01, out);
}

// Round 7
// 493.213 us; speedup vs baseline: 1.1081x; 1.0169x over previous
//
#include <hip/hip_runtime.h>
#include <hip/hip_bf16.h>
#include <math.h>
#include <stdint.h>

#define BT  4096
#define DIM 1024
#define HID 4096
#define NE  8
#define TMX 72   // max active 128-row m-blocks (64 full + 8 partial)

typedef __attribute__((ext_vector_type(8))) short short8v;
typedef __attribute__((ext_vector_type(4))) float f32x4;
typedef unsigned short ushort_t;

typedef __attribute__((address_space(1))) const void gas_void;
typedef __attribute__((address_space(3))) void las_void;
#define GLOAD_LDS16(g, l) __builtin_amdgcn_global_load_lds((gas_void*)(g), (las_void*)(l), 16, 0, 0)

__device__ inline ushort_t f2bf(float f) {
  __hip_bfloat16 b = __float2bfloat16(f);
  union { __hip_bfloat16 h; ushort_t u; } cv;
  cv.h = b;
  return cv.u;
}

// -------- fused prep + router: one block per token --------
__global__ __launch_bounds__(256) void k_prep_router(
    const float* __restrict__ x, const float* __restrict__ wg,
    ushort_t* __restrict__ xbf, float* __restrict__ logits_out,
    float* __restrict__ probs01, int* __restrict__ assign,
    int* __restrict__ cur) {
  int t = blockIdx.x;
  int tid = threadIdx.x;
  const float* xr = x + (size_t)t * DIM;
  float4 v = ((const float4*)xr)[tid];
  ushort4 o;
  o.x = f2bf(v.x); o.y = f2bf(v.y); o.z = f2bf(v.z); o.w = f2bf(v.w);
  ((ushort4*)(xbf + (size_t)t * DIM))[tid] = o;

  float vv[4] = {v.x, v.y, v.z, v.w};
  float part[NE];
#pragma unroll
  for (int e = 0; e < NE; e++) part[e] = 0.f;
#pragma unroll
  for (int i = 0; i < 4; i++) {
    const float4* wr = (const float4*)(wg + (size_t)(tid * 4 + i) * NE);
    float4 a = wr[0], b = wr[1];
    part[0] += vv[i] * a.x; part[1] += vv[i] * a.y;
    part[2] += vv[i] * a.z; part[3] += vv[i] * a.w;
    part[4] += vv[i] * b.x; part[5] += vv[i] * b.y;
    part[6] += vv[i] * b.z; part[7] += vv[i] * b.w;
  }
#pragma unroll
  for (int e = 0; e < NE; e++)
    for (int off = 32; off > 0; off >>= 1)
      part[e] += __shfl_xor(part[e], off);

  __shared__ float red[4][NE];
  int lane = tid & 63, wv = tid >> 6;
  if (lane == 0) {
#pragma unroll
    for (int e = 0; e < NE; e++) red[wv][e] = part[e];
  }
  __syncthreads();
  if (tid == 0) {
    float s8[NE];
#pragma unroll
    for (int e = 0; e < NE; e++)
      s8[e] = red[0][e] + red[1][e] + red[2][e] + red[3][e];
    float m = s8[0];
    for (int e = 1; e < NE; e++) m = fmaxf(m, s8[e]);
    float p[NE], s = 0.f;
    for (int e = 0; e < NE; e++) { p[e] = expf(s8[e] - m); s += p[e]; }
    float inv = 1.f / s;
    for (int e = 0; e < NE; e++) p[e] *= inv;
    for (int e = 0; e < NE; e++) logits_out[(size_t)t * NE + e] = s8[e];
    probs01[t * 2 + 0] = p[0];
    probs01[t * 2 + 1] = p[1];
    int b0 = 0;
    for (int e = 1; e < NE; e++) if (p[e] > p[b0]) b0 = e;
    int b1 = (b0 == 0) ? 1 : 0;
    for (int e = 0; e < NE; e++) if (e != b0 && p[e] > p[b1]) b1 = e;
    int pos0 = atomicAdd(&cur[b0], 1);
    assign[b0 * BT + pos0] = t * 2 + 0;
    int pos1 = atomicAdd(&cur[b1], 1);
    assign[b1 * BT + pos1] = t * 2 + 1;
  }
}

// -------- transpose+convert: src fp32 [E][R][C] -> dst bf16 [E][C][R] --------
// Also zeros cur[] (runs before k_prep_router in stream order).
__global__ __launch_bounds__(256) void k_transpose(const float* __restrict__ src,
                                                   ushort_t* __restrict__ dst,
                                                   int R, int C,
                                                   int* __restrict__ cur) {
  if (cur && blockIdx.x == 0 && blockIdx.y == 0 && blockIdx.z == 0 &&
      threadIdx.x < NE)
    cur[threadIdx.x] = 0;
  __shared__ float tile[64][65];
  int e = blockIdx.z;
  const float* s = src + (size_t)e * R * C;
  ushort_t* d = dst + (size_t)e * R * C;
  int c0 = blockIdx.x * 64, r0 = blockIdx.y * 64;
  int t = threadIdx.x;
  int lr = t >> 4;
  int lc4 = (t & 15) * 4;
#pragma unroll
  for (int i = 0; i < 4; i++) {
    int r = lr + 16 * i;
    float4 v = *(const float4*)&s[(size_t)(r0 + r) * C + c0 + lc4];
    tile[r][lc4 + 0] = v.x; tile[r][lc4 + 1] = v.y;
    tile[r][lc4 + 2] = v.z; tile[r][lc4 + 3] = v.w;
  }
  __syncthreads();
  int c = t >> 3, r8 = (t & 7) * 8;
#pragma unroll
  for (int p = 0; p < 2; p++) {
    int cc = c + 32 * p;
    short8v ov;
#pragma unroll
    for (int i = 0; i < 8; i++) ov[i] = (short)f2bf(tile[r8 + i][cc]);
    *(short8v*)&d[(size_t)(c0 + cc) * R + r0 + r8] = ov;
  }
}

// -------- plan: prefix offsets + flattened active 128-row block list --------
__global__ void k_plan(const int* __restrict__ cur, int* __restrict__ segoff,
                       int* __restrict__ blk_e, int* __restrict__ blk_m0) {
  int tid = threadIdx.x;
  if (tid == 0 && blockIdx.x == 0) {
    int s = 0;
    for (int e = 0; e < NE; e++) { segoff[e] = s; s += cur[e]; }
    int t = 0;
    for (int e = 0; e < NE; e++) {
      int mb = (cur[e] + 127) >> 7;
      for (int i = 0; i < mb; i++) { blk_e[t] = e; blk_m0[t] = i << 7; t++; }
    }
    for (; t < TMX; t++) { blk_e[t] = -1; blk_m0[t] = 0; }
  }
}

// ============================================================================
// K-tile body: 128x128 tile, BK=32, ring-4 LDS = 64 KiB -> 2 blocks/CU.
// 256 thr = 4 waves (2M x 2N), wave tile 64x64, acc[4][4].
// Per K-tile: { 8 ds_reads(tile TB) -> stage(t+3): 4 gloads -> vmcnt(8) ->
//   barrier (publishes t+1) -> sched_barrier -> setprio -> 16 MFMA }.
// Inter-block TLP is the point: when this block stalls at vmcnt/barrier,
// the co-resident block's waves keep the MFMA/LDS pipes fed (m114).
// vmcnt ledger (4 loads/tile/wave): steady vmcnt(8); tail 8,4,0.
// Slot safety: stage(t+3) overwrites slot (t-1)&3, whose ds_reads were
// issued before barrier#(t-1); gload LDS-write lands >=200cyc after issue
// (post-barrier) vs ds_read capture ~120cyc -- same discipline as R4-R6
// (3x harness-verified bit-identical).
// ============================================================================
#define VM8 asm volatile("s_waitcnt vmcnt(8)" ::: "memory")
#define VM4 asm volatile("s_waitcnt vmcnt(4)" ::: "memory")
#define VM0 asm volatile("s_waitcnt vmcnt(0)" ::: "memory")
#define VMN do {} while (0)

#define TILEK(TB, T, VMX, DOSTG)                                                \
  { short8v bv[4], af[4];                                                       \
    _Pragma("unroll")                                                           \
    for (int n = 0; n < 4; n++)                                                 \
      bv[n] = *(const short8v*)&Bv[TB][wn * 64 + n * 16 + lr][xsw];             \
    _Pragma("unroll")                                                           \
    for (int m = 0; m < 4; m++)                                                 \
      af[m] = *(const short8v*)&A[TB][wm * 64 + m * 16 + lr][xsw];              \
    if (DOSTG) { STAGE((((TB) + 3) & 3), ((T) + 3) * 32); }                     \
    VMX;                                                                        \
    __builtin_amdgcn_s_barrier();                                               \
    __builtin_amdgcn_sched_barrier(0);                                          \
    __builtin_amdgcn_s_setprio(1);                                              \
    _Pragma("unroll")                                                           \
    for (int m = 0; m < 4; m++)                                                 \
      _Pragma("unroll")                                                         \
      for (int n = 0; n < 4; n++)                                               \
        acc[m][n] = __builtin_amdgcn_mfma_f32_16x16x32_bf16(af[m], bv[n],       \
                                                            acc[m][n], 0, 0, 0);\
    __builtin_amdgcn_s_setprio(0); }

// ============================================================================
// GEMM1: h = gelu(x_gathered @ w1^T + b1).  Grid 32n x TMX(72)m = 2304.
// ============================================================================
__global__ __launch_bounds__(256, 2) void k_gemm1(
    const ushort_t* __restrict__ xbf, const ushort_t* __restrict__ wt1,
    const float* __restrict__ b1,
    const int* __restrict__ assign, const int* __restrict__ cur,
    const int* __restrict__ segoff, const int* __restrict__ blk_e,
    const int* __restrict__ blk_m0, ushort_t* __restrict__ hbuf) {
  const int nwg = 32 * TMX;                    // 2304, divisible by 8
  int f = blockIdx.x;
  int lg = (f & 7) * (nwg >> 3) + (f >> 3);    // XCD chunk swizzle (bijective)
  int m_idx = lg % TMX;                        // m-inner: chunk reuses B-panels
  int n_idx = lg / TMX;
  int e = blk_e[m_idx];
  if (e < 0) return;
  int m0 = blk_m0[m_idx];
  int count = cur[e];
  int n0 = n_idx << 7;

  __shared__ __attribute__((aligned(16))) ushort_t A[4][128][32];
  __shared__ __attribute__((aligned(16))) ushort_t Bv[4][128][32];
  int tid = threadIdx.x;
  int lane = tid & 63, wid = tid >> 6;

  int srow = lane >> 2;
  int sunit = ((lane & 3) ^ ((lane >> 3) & 3)) << 3;
  int pA0 = m0 + wid * 16 + srow;
  int pA1 = pA0 + 64;
  int tok0 = (pA0 < count) ? (assign[e * BT + pA0] >> 1) : 0;
  int tok1 = (pA1 < count) ? (assign[e * BT + pA1] >> 1) : 0;
  const ushort_t* gA0 = xbf + (size_t)tok0 * DIM + sunit;
  const ushort_t* gA1 = xbf + (size_t)tok1 * DIM + sunit;
  const ushort_t* gB0 = wt1 + ((size_t)e * HID + n0 + wid * 16 + srow) * DIM + sunit;
  const ushort_t* gB1 = gB0 + (size_t)64 * DIM;

  int wm = wid >> 1, wn = wid & 1;             // wave tile: 64(m) x 64(n)
  int lr = lane & 15, g = lane >> 4;
  int xsw = ((g ^ ((lr >> 1) & 3)) << 3);
  f32x4 acc[4][4];
  f32x4 zero = {0.f, 0.f, 0.f, 0.f};
#pragma unroll
  for (int m = 0; m < 4; m++)
#pragma unroll
    for (int n = 0; n < 4; n++) acc[m][n] = zero;

#define STAGE(SL, K0)                                          \
  { GLOAD_LDS16(gA0 + (K0), &A[SL][wid * 16][0]);              \
    GLOAD_LDS16(gA1 + (K0), &A[SL][64 + wid * 16][0]);         \
    GLOAD_LDS16(gB0 + (K0), &Bv[SL][wid * 16][0]);             \
    GLOAD_LDS16(gB1 + (K0), &Bv[SL][64 + wid * 16][0]); }

  STAGE(0, 0);
  STAGE(1, 32);
  STAGE(2, 64);
  VM8;
  __builtin_amdgcn_s_barrier();
  __builtin_amdgcn_sched_barrier(0);

  const int NT = DIM / 32;                     // 32
  for (int t = 0; t < NT - 4; t += 4) {
    TILEK(0, t + 0, VM8, 1);
    TILEK(1, t + 1, VM8, 1);
    TILEK(2, t + 2, VM8, 1);
    TILEK(3, t + 3, VM8, 1);
  }
  TILEK(0, NT - 4, VM8, 1);
  TILEK(1, NT - 3, VM4, 0);
  TILEK(2, NT - 2, VM0, 0);
  TILEK(3, NT - 1, VMN, 0);
#undef STAGE

  int so = segoff[e];
#pragma unroll
  for (int m = 0; m < 4; m++) {
#pragma unroll
    for (int j = 0; j < 4; j++) {
      int p = m0 + wm * 64 + m * 16 + g * 4 + j;
      if (p >= count) continue;
      ushort_t* hr = hbuf + (size_t)(so + p) * HID;
#pragma unroll
      for (int n = 0; n < 4; n++) {
        int col = n0 + wn * 64 + n * 16 + lr;
        float v = acc[m][n][j] + b1[e * HID + col];
        float gl = 0.5f * v * (1.0f + erff(v * 0.70710678118654752f));
        hr[col] = f2bf(gl);
      }
    }
  }
}

// ============================================================================
// GEMM2: contrib[slot][t] = h @ w2^T + b2.  Grid 8n x TMX(72)m = 576.
// ============================================================================
__global__ __launch_bounds__(256, 2) void k_gemm2(
    const ushort_t* __restrict__ hbuf, const ushort_t* __restrict__ wt2,
    const float* __restrict__ b2,
    const int* __restrict__ assign, const int* __restrict__ cur,
    const int* __restrict__ segoff, const int* __restrict__ blk_e,
    const int* __restrict__ blk_m0, float* __restrict__ contrib) {
  const int nwg = 8 * TMX;                     // 576, divisible by 8
  int f = blockIdx.x;
  int lg = (f & 7) * (nwg >> 3) + (f >> 3);
  int m_idx = lg % TMX;
  int n_idx = lg / TMX;
  int e = blk_e[m_idx];
  if (e < 0) return;
  int m0 = blk_m0[m_idx];
  int count = cur[e];
  int n0 = n_idx << 7;
  int so = segoff[e];

  __shared__ __attribute__((aligned(16))) ushort_t A[4][128][32];
  __shared__ __attribute__((aligned(16))) ushort_t Bv[4][128][32];
  int tid = threadIdx.x;
  int lane = tid & 63, wid = tid >> 6;

  int srow = lane >> 2;
  int sunit = ((lane & 3) ^ ((lane >> 3) & 3)) << 3;
  int pA0 = m0 + wid * 16 + srow;
  int pA1 = pA0 + 64;
  int pa0 = (pA0 < count) ? pA0 : (count - 1);
  int pa1 = (pA1 < count) ? pA1 : (count - 1);
  const ushort_t* gA0 = hbuf + (size_t)(so + pa0) * HID + sunit;
  const ushort_t* gA1 = hbuf + (size_t)(so + pa1) * HID + sunit;
  const ushort_t* gB0 = wt2 + ((size_t)e * DIM + n0 + wid * 16 + srow) * HID + sunit;
  const ushort_t* gB1 = gB0 + (size_t)64 * HID;

  int wm = wid >> 1, wn = wid & 1;             // wave tile: 64(m) x 64(n)
  int lr = lane & 15, g = lane >> 4;
  int xsw = ((g ^ ((lr >> 1) & 3)) << 3);
  f32x4 acc[4][4];
  f32x4 zero = {0.f, 0.f, 0.f, 0.f};
#pragma unroll
  for (int m = 0; m < 4; m++)
#pragma unroll
    for (int n = 0; n < 4; n++) acc[m][n] = zero;

#define STAGE(SL, K0)                                          \
  { GLOAD_LDS16(gA0 + (K0), &A[SL][wid * 16][0]);              \
    GLOAD_LDS16(gA1 + (K0), &A[SL][64 + wid * 16][0]);         \
    GLOAD_LDS16(gB0 + (K0), &Bv[SL][wid * 16][0]);             \
    GLOAD_LDS16(gB1 + (K0), &Bv[SL][64 + wid * 16][0]); }

  STAGE(0, 0);
  STAGE(1, 32);
  STAGE(2, 64);
  VM8;
  __builtin_amdgcn_s_barrier();
  __builtin_amdgcn_sched_barrier(0);

  const int NT = HID / 32;                     // 128
  for (int t = 0; t < NT - 4; t += 4) {
    TILEK(0, t + 0, VM8, 1);
    TILEK(1, t + 1, VM8, 1);
    TILEK(2, t + 2, VM8, 1);
    TILEK(3, t + 3, VM8, 1);
  }
  TILEK(0, NT - 4, VM8, 1);
  TILEK(1, NT - 3, VM4, 0);
  TILEK(2, NT - 2, VM0, 0);
  TILEK(3, NT - 1, VMN, 0);
#undef STAGE

#pragma unroll
  for (int m = 0; m < 4; m++) {
#pragma unroll
    for (int j = 0; j < 4; j++) {
      int p = m0 + wm * 64 + m * 16 + g * 4 + j;
      if (p >= count) continue;
      int a = assign[e * BT + p];
      int t = a >> 1, slot = a & 1;
      float* cr = contrib + ((size_t)slot * BT + t) * DIM;
#pragma unroll
      for (int n = 0; n < 4; n++) {
        int col = n0 + wn * 64 + n * 16 + lr;
        cr[col] = acc[m][n][j] + b2[e * DIM + col];
      }
    }
  }
}

// -------- combine: final = c0*probs[:,0] + c1*probs[:,1] --------
__global__ void k_combine(const float* __restrict__ contrib,
                          const float* __restrict__ probs01,
                          float* __restrict__ out) {
  int idx = blockIdx.x * blockDim.x + threadIdx.x;
  const int n4 = BT * DIM / 4;
  if (idx >= n4) return;
  int t = idx >> 8;
  float wA = probs01[t * 2 + 0], wB = probs01[t * 2 + 1];
  float4 c0 = ((const float4*)contrib)[idx];
  float4 c1 = ((const float4*)(contrib + (size_t)BT * DIM))[idx];
  float4 o;
  o.x = c0.x * wA + c1.x * wB;
  o.y = c0.y * wA + c1.y * wB;
  o.z = c0.z * wA + c1.z * wB;
  o.w = c0.w * wA + c1.w * wB;
  ((float4*)out)[idx] = o;
}

extern "C" void kernel_launch(void* const* d_in, const int* in_sizes, int n_in,
                              void* d_out, int out_size, void* d_ws, size_t ws_size,
                              hipStream_t stream) {
  const float* x  = (const float*)d_in[0];
  const float* wg = (const float*)d_in[1];
  const float* w1 = (const float*)d_in[2];
  const float* b1 = (const float*)d_in[3];
  const float* w2 = (const float*)d_in[4];
  const float* b2 = (const float*)d_in[5];
  float* out = (float*)d_out;
  float* logits_out = out + (size_t)BT * DIM;

  char* ws = (char*)d_ws;
  size_t off = 0;
  auto alloc = [&](size_t bytes) -> void* {
    void* p = ws + off;
    off = (off + bytes + 255) & ~(size_t)255;
    return p;
  };
  ushort_t* xbf    = (ushort_t*)alloc((size_t)BT * DIM * 2);
  ushort_t* wt1    = (ushort_t*)alloc((size_t)NE * HID * DIM * 2);
  ushort_t* wt2    = (ushort_t*)alloc((size_t)NE * DIM * HID * 2);
  ushort_t* hbuf   = (ushort_t*)alloc((size_t)2 * BT * HID * 2);
  float*    contrib= (float*)alloc((size_t)2 * BT * DIM * 4);
  float*    probs01= (float*)alloc((size_t)BT * 2 * 4);
  int*      assign = (int*)alloc((size_t)NE * BT * 4);
  int*      cur    = (int*)alloc(64);
  int*      segoff = (int*)alloc(64);
  int*      blk_e  = (int*)alloc(TMX * 4);
  int*      blk_m0 = (int*)alloc(TMX * 4);
  if (off > ws_size) return;

  // transpose(w1) also zeros cur; stream order puts it before k_prep_router.
  hipLaunchKernelGGL(k_transpose, dim3(HID / 64, DIM / 64, NE), dim3(256), 0, stream,
                     w1, wt1, DIM, HID, cur);
  hipLaunchKernelGGL(k_transpose, dim3(DIM / 64, HID / 64, NE), dim3(256), 0, stream,
                     w2, wt2, HID, DIM, (int*)nullptr);
  hipLaunchKernelGGL(k_prep_router, dim3(BT), dim3(256), 0, stream,
                     x, wg, xbf, logits_out, probs01, assign, cur);
  hipLaunchKernelGGL(k_plan, dim3(1), dim3(64), 0, stream, cur, segoff,
                     blk_e, blk_m0);
  hipLaunchKernelGGL(k_gemm1, dim3(32 * TMX), dim3(256), 0, stream,
                     xbf, wt1, b1, assign, cur, segoff, blk_e, blk_m0, hbuf);
  hipLaunchKernelGGL(k_gemm2, dim3(8 * TMX), dim3(256), 0, stream,
                     hbuf, wt2, b2, assign, cur, segoff, blk_e, blk_m0, contrib);
  hipLaunchKernelGGL(k_combine, dim3((BT * DIM / 4 + 255) / 256), dim3(256), 0, stream,
                     contrib, probs01, out);
}